// Round 1
// baseline (8914.910 us; speedup 1.0000x reference)
//
#include <hip/hip_runtime.h>
#include <hip/hip_fp16.h>

#define B_  256
#define T_  96
#define IN_ 512
#define H_  1024
#define K1  1536          // H + IN
#define NT  (B_*T_)       // 24576

typedef _Float16 f16x8 __attribute__((ext_vector_type(8)));
typedef float    f32x4 __attribute__((ext_vector_type(4)));

__device__ __forceinline__ float sigmoidf_(float z) { return 1.f/(1.f+__expf(-z)); }
__device__ __forceinline__ float tanhf_(float z)    { return 1.f - 2.f/(__expf(2.f*z)+1.f); }

// ---------------- prep: fp32 -> fp16 conversions ----------------
__global__ void cvt_f32_f16_k(const float* __restrict__ src, _Float16* __restrict__ dst, int n8) {
    int i = blockIdx.x*blockDim.x + threadIdx.x;
    if (i >= n8) return;
    const float4* s = (const float4*)src;
    float4 a = s[2*(size_t)i], b = s[2*(size_t)i+1];
    f16x8 o;
    o[0]=(_Float16)a.x; o[1]=(_Float16)a.y; o[2]=(_Float16)a.z; o[3]=(_Float16)a.w;
    o[4]=(_Float16)b.x; o[5]=(_Float16)b.y; o[6]=(_Float16)b.z; o[7]=(_Float16)b.w;
    *(f16x8*)(dst + 8*(size_t)i) = o;
}

__global__ void pack_w12_k(const float* __restrict__ W1, const float* __restrict__ W2,
                           _Float16* __restrict__ dst) {
    int i = blockIdx.x*blockDim.x + threadIdx.x;   // over 2048*1536/8 units
    int n8 = 2048*K1/8;
    if (i >= n8) return;
    size_t e = 8*(size_t)i;
    const float* src = (e < (size_t)H_*K1) ? (W1 + e) : (W2 + e - (size_t)H_*K1);
    float4 a = *(const float4*)src;
    float4 b = *(const float4*)(src+4);
    f16x8 o;
    o[0]=(_Float16)a.x; o[1]=(_Float16)a.y; o[2]=(_Float16)a.z; o[3]=(_Float16)a.w;
    o[4]=(_Float16)b.x; o[5]=(_Float16)b.y; o[6]=(_Float16)b.z; o[7]=(_Float16)b.w;
    *(f16x8*)(dst + e) = o;
}

// ---------------- belta = exp(-relu(td @ Wb^T + bb)) ----------------
// GEMM (24576 x 512) @ (1024 x 512)^T, tile 64x128, 256 thr (4 waves, 32x64 each)
__global__ void __launch_bounds__(256) belta_gemm_k(const _Float16* __restrict__ td,
                                                    const _Float16* __restrict__ Wbh,
                                                    const float* __restrict__ bb,
                                                    _Float16* __restrict__ belta) {
    __shared__ _Float16 As[64][136];
    __shared__ _Float16 Bs[128][136];
    const int bid = blockIdx.x;
    const int mt = bid >> 3, nt = bid & 7;
    const int bt0 = mt*64, h0 = nt*128;
    const int tid = threadIdx.x;
    const int w = tid >> 6, l = tid & 63;
    const int wm = (w>>1)*32, wn = (w&1)*64;
    f32x4 acc[2][4] = {};
    for (int kc = 0; kc < 4; ++kc) {
        const int kbase = kc*128;
        #pragma unroll
        for (int p = 0; p < 4; ++p) {                 // A: 64 rows x 16 units
            int unit = tid + 256*p; int r = unit>>4, cu = unit&15;
            *(uint4*)&As[r][cu*8] = *(const uint4*)(td + (size_t)(bt0+r)*IN_ + kbase + cu*8);
        }
        #pragma unroll
        for (int p = 0; p < 8; ++p) {                 // B: 128 rows x 16 units
            int unit = tid + 256*p; int r = unit>>4, cu = unit&15;
            *(uint4*)&Bs[r][cu*8] = *(const uint4*)(Wbh + (size_t)(h0+r)*IN_ + kbase + cu*8);
        }
        __syncthreads();
        #pragma unroll
        for (int ks = 0; ks < 4; ++ks) {
            const int kk = ks*32 + (l>>4)*8;
            f16x8 a0 = *(const f16x8*)&As[wm +      (l&15)][kk];
            f16x8 a1 = *(const f16x8*)&As[wm + 16 + (l&15)][kk];
            #pragma unroll
            for (int ni = 0; ni < 4; ++ni) {
                f16x8 b = *(const f16x8*)&Bs[wn + ni*16 + (l&15)][kk];
                acc[0][ni] = __builtin_amdgcn_mfma_f32_16x16x32_f16(a0, b, acc[0][ni], 0,0,0);
                acc[1][ni] = __builtin_amdgcn_mfma_f32_16x16x32_f16(a1, b, acc[1][ni], 0,0,0);
            }
        }
        __syncthreads();
    }
    #pragma unroll
    for (int mi = 0; mi < 2; ++mi)
    #pragma unroll
    for (int ni = 0; ni < 4; ++ni)
    #pragma unroll
    for (int r = 0; r < 4; ++r) {
        int m_l = wm + mi*16 + (l>>4)*4 + r;
        int n_l = wn + ni*16 + (l&15);
        int bt = bt0 + m_l, h = h0 + n_l;
        float z = acc[mi][ni][r] + bb[h];
        belta[(size_t)bt*H_ + h] = (_Float16)__expf(-fmaxf(z, 0.f));
    }
}

// ---------------- grid barrier (single-stage, agent scope) ----------------
__device__ __forceinline__ void grid_barrier(int* flags, int it) {
    __syncthreads();
    if (threadIdx.x == 0)
        __hip_atomic_store(&flags[blockIdx.x], it, __ATOMIC_RELEASE, __HIP_MEMORY_SCOPE_AGENT);
    for (;;) {
        int v = __hip_atomic_load(&flags[threadIdx.x], __ATOMIC_ACQUIRE, __HIP_MEMORY_SCOPE_AGENT);
        if (__syncthreads_count(v < it) == 0) break;
        __builtin_amdgcn_s_sleep(2);
    }
}

// ---------------- recurrent scan: 96 steps, 2 GEMMs/step ----------------
__global__ void __launch_bounds__(256) recur_k(
    const _Float16* __restrict__ xh,     // (B,T,IN)
    const _Float16* __restrict__ belta,  // (B,T,H)
    const _Float16* __restrict__ W12h,   // (2048,1536) rows: [W1 | W2]
    const _Float16* __restrict__ W3h,    // (1024,1536)
    const float* __restrict__ b1, const float* __restrict__ b2, const float* __restrict__ b3,
    const float* __restrict__ Wo, const float* __restrict__ bo,
    float* __restrict__ S,               // (256,1024) fp32: holds belta_t * s_{t-1}
    _Float16* __restrict__ ssh,          // fp16 mirror of S (GEMM A operand)
    float* __restrict__ U,               // (256,1024)
    _Float16* __restrict__ rsh,          // (256,1024) r * sstate
    int* flags, float* __restrict__ out)
{
    __shared__ _Float16 As[32][136];
    __shared__ _Float16 Bs[64][136];
    __shared__ float red[4];
    const int bid = blockIdx.x, tid = threadIdx.x;
    const int w = tid>>6, l = tid&63;
    const int mg = bid>>5, ng = bid&31;
    const int m0 = mg*32;
    int it = 0;

    for (int t = 0; t < T_; ++t) {
        { // ---- P1: [u|r] = sigmoid([sstate|x_t] @ W12^T + b12), tile 32x64 ----
            const int n0 = ng*64;
            const int wm = (w>>1)*16, wn = (w&1)*32;
            f32x4 acc[2] = {};
            for (int kc = 0; kc < 12; ++kc) {
                const int kbase = kc*128;
                #pragma unroll
                for (int p = 0; p < 2; ++p) {         // A: 32 rows
                    int unit = tid + 256*p; int r = unit>>4, cu = unit&15;
                    int k = kbase + cu*8;
                    const _Float16* src = (k < H_)
                        ? (ssh + (size_t)(m0+r)*H_ + k)
                        : (xh + ((size_t)(m0+r)*T_ + t)*IN_ + (k - H_));
                    *(uint4*)&As[r][cu*8] = *(const uint4*)src;
                }
                #pragma unroll
                for (int p = 0; p < 4; ++p) {         // B: 64 rows
                    int unit = tid + 256*p; int r = unit>>4, cu = unit&15;
                    *(uint4*)&Bs[r][cu*8] = *(const uint4*)(W12h + (size_t)(n0+r)*K1 + kbase + cu*8);
                }
                __syncthreads();
                #pragma unroll
                for (int ks = 0; ks < 4; ++ks) {
                    const int kk = ks*32 + (l>>4)*8;
                    f16x8 a = *(const f16x8*)&As[wm + (l&15)][kk];
                    #pragma unroll
                    for (int ni = 0; ni < 2; ++ni) {
                        f16x8 b = *(const f16x8*)&Bs[wn + ni*16 + (l&15)][kk];
                        acc[ni] = __builtin_amdgcn_mfma_f32_16x16x32_f16(a, b, acc[ni], 0,0,0);
                    }
                }
                __syncthreads();
            }
            #pragma unroll
            for (int ni = 0; ni < 2; ++ni)
            #pragma unroll
            for (int r = 0; r < 4; ++r) {
                int m = m0 + wm + (l>>4)*4 + r;
                int n = n0 + wn + ni*16 + (l&15);
                float z = acc[ni][r];
                if (n < H_) {
                    U[(size_t)m*H_ + n] = sigmoidf_(z + b1[n]);
                } else {
                    int h = n - H_;
                    float rr = sigmoidf_(z + b2[h]);
                    rsh[(size_t)m*H_ + h] = (_Float16)(rr * S[(size_t)m*H_ + h]);
                }
            }
        }
        grid_barrier(flags, ++it);
        { // ---- P2: nst = tanh([r*sstate|x_t] @ W3^T + b3); state update; tile 32x32 ----
            const int n0 = ng*32;
            const int wm = (w>>1)*16, wn = (w&1)*16;
            f32x4 acc = {};
            for (int kc = 0; kc < 12; ++kc) {
                const int kbase = kc*128;
                #pragma unroll
                for (int p = 0; p < 2; ++p) {         // A: 32 rows
                    int unit = tid + 256*p; int r = unit>>4, cu = unit&15;
                    int k = kbase + cu*8;
                    const _Float16* src = (k < H_)
                        ? (rsh + (size_t)(m0+r)*H_ + k)
                        : (xh + ((size_t)(m0+r)*T_ + t)*IN_ + (k - H_));
                    *(uint4*)&As[r][cu*8] = *(const uint4*)src;
                }
                #pragma unroll
                for (int p = 0; p < 2; ++p) {         // B: 32 rows
                    int unit = tid + 256*p; int r = unit>>4, cu = unit&15;
                    *(uint4*)&Bs[r][cu*8] = *(const uint4*)(W3h + (size_t)(n0+r)*K1 + kbase + cu*8);
                }
                __syncthreads();
                #pragma unroll
                for (int ks = 0; ks < 4; ++ks) {
                    const int kk = ks*32 + (l>>4)*8;
                    f16x8 a = *(const f16x8*)&As[wm + (l&15)][kk];
                    f16x8 b = *(const f16x8*)&Bs[wn + (l&15)][kk];
                    acc = __builtin_amdgcn_mfma_f32_16x16x32_f16(a, b, acc, 0,0,0);
                }
                __syncthreads();
            }
            #pragma unroll
            for (int r = 0; r < 4; ++r) {
                int m = m0 + wm + (l>>4)*4 + r;
                int n = n0 + wn + (l&15);
                size_t idx = (size_t)m*H_ + n;
                float nst = tanhf_(acc[r] + b3[n]);
                float u = U[idx];
                float snew = (1.f - u)*S[idx] + u*nst;
                if (t < T_-1) {
                    float bel = (float)belta[((size_t)m*T_ + (t+1))*H_ + n];
                    float ss = bel * snew;
                    S[idx] = ss;
                    ssh[idx] = (_Float16)ss;
                } else {
                    S[idx] = snew;   // final state unscaled
                }
            }
        }
        grid_barrier(flags, ++it);
    }
    // ---- final: out[b] = sigmoid(S[b,:] . Wo + bo), block bid -> row bid ----
    {
        float sum = 0.f;
        for (int h = tid; h < H_; h += 256) sum += S[(size_t)bid*H_ + h]*Wo[h];
        #pragma unroll
        for (int off = 32; off; off >>= 1) sum += __shfl_down(sum, off, 64);
        if (l == 0) red[w] = sum;
        __syncthreads();
        if (tid == 0) out[bid] = sigmoidf_(red[0]+red[1]+red[2]+red[3] + bo[0]);
    }
}

extern "C" void kernel_launch(void* const* d_in, const int* in_sizes, int n_in,
                              void* d_out, int out_size, void* d_ws, size_t ws_size,
                              hipStream_t stream) {
    const float* x   = (const float*)d_in[0];
    const float* td  = (const float*)d_in[1];
    const float* Wb  = (const float*)d_in[2];
    const float* bb  = (const float*)d_in[3];
    const float* W1  = (const float*)d_in[4];
    const float* b1  = (const float*)d_in[5];
    const float* W2  = (const float*)d_in[6];
    const float* b2  = (const float*)d_in[7];
    const float* W3  = (const float*)d_in[8];
    const float* b3  = (const float*)d_in[9];
    const float* Wo  = (const float*)d_in[10];
    const float* bo  = (const float*)d_in[11];
    float* out = (float*)d_out;

    char* p = (char*)d_ws;
    auto carve = [&](size_t bytes) { char* r = p; p += (bytes + 255) & ~(size_t)255; return r; };
    int*      bar  = (int*)      carve(4096);
    float*    S    = (float*)    carve((size_t)B_*H_*4);
    _Float16* ssh  = (_Float16*) carve((size_t)B_*H_*2);
    float*    U    = (float*)    carve((size_t)B_*H_*4);
    _Float16* rsh  = (_Float16*) carve((size_t)B_*H_*2);
    _Float16* xh   = (_Float16*) carve((size_t)NT*IN_*2);
    _Float16* tdh  = (_Float16*) carve((size_t)NT*IN_*2);
    _Float16* belh = (_Float16*) carve((size_t)NT*H_*2);
    _Float16* W12h = (_Float16*) carve((size_t)2048*K1*2);
    _Float16* W3h  = (_Float16*) carve((size_t)H_*K1*2);
    _Float16* Wbh  = (_Float16*) carve((size_t)H_*IN_*2);

    // zero barrier flags + S + ssh (contiguous)
    size_t zbytes = 4096 + (size_t)B_*H_*4 + (size_t)B_*H_*2;
    hipMemsetAsync(bar, 0, zbytes, stream);

    const int thr = 256;
    int n8;
    n8 = NT*IN_/8;    cvt_f32_f16_k<<<(n8+thr-1)/thr, thr, 0, stream>>>(x,  xh,  n8);
    n8 = NT*IN_/8;    cvt_f32_f16_k<<<(n8+thr-1)/thr, thr, 0, stream>>>(td, tdh, n8);
    n8 = H_*K1/8;     cvt_f32_f16_k<<<(n8+thr-1)/thr, thr, 0, stream>>>(W3, W3h, n8);
    n8 = H_*IN_/8;    cvt_f32_f16_k<<<(n8+thr-1)/thr, thr, 0, stream>>>(Wb, Wbh, n8);
    n8 = 2048*K1/8;   pack_w12_k<<<(n8+thr-1)/thr, thr, 0, stream>>>(W1, W2, W12h);

    belta_gemm_k<<<(NT/64)*(H_/128), 256, 0, stream>>>(tdh, Wbh, bb, belh);

    recur_k<<<256, 256, 0, stream>>>(xh, belh, W12h, W3h, b1, b2, b3, Wo, bo,
                                     S, ssh, U, rsh, bar, out);
}

// Round 2
// 4261.151 us; speedup vs baseline: 2.0921x; 2.0921x over previous
//
#include <hip/hip_runtime.h>
#include <hip/hip_fp16.h>

#define B_  256
#define T_  96
#define IN_ 512
#define H_  1024
#define K1  1536          // H + IN
#define NT  (B_*T_)       // 24576

typedef _Float16 f16x8 __attribute__((ext_vector_type(8)));
typedef float    f32x4 __attribute__((ext_vector_type(4)));

__device__ __forceinline__ float sigmoidf_(float z) { return 1.f/(1.f+__expf(-z)); }
__device__ __forceinline__ float tanhf_(float z)    { return 1.f - 2.f/(__expf(2.f*z)+1.f); }

// ---- coherent (cross-XCD) access helpers ----
// sc0 sc1 on gfx950 = force to coherence point (bypass L1 + per-XCD L2).
// Lines never sit dirty/stale in a non-coherent L2, so NO wbl2/invl2 is ever
// needed -> weights stay L2-resident across grid barriers.
__device__ __forceinline__ uint4 ld_coh_b128_nw(const void* p){
    uint4 r; asm volatile("global_load_dwordx4 %0, %1, off sc0 sc1" : "=v"(r) : "v"(p)); return r;
}
__device__ __forceinline__ uint2 ld_coh_b64_nw(const void* p){
    uint2 r; asm volatile("global_load_dwordx2 %0, %1, off sc0 sc1" : "=v"(r) : "v"(p)); return r;
}
__device__ __forceinline__ unsigned ld_coh_u16_nw(const void* p){
    unsigned r; asm volatile("global_load_ushort %0, %1, off sc0 sc1" : "=v"(r) : "v"(p)); return r;
}
__device__ __forceinline__ unsigned ld_coh_u32_nw(const void* p){
    unsigned r; asm volatile("global_load_dword %0, %1, off sc0 sc1" : "=v"(r) : "v"(p)); return r;
}
__device__ __forceinline__ void st_coh_u32(void* p, unsigned v){
    asm volatile("global_store_dword %0, %1, off sc0 sc1" :: "v"(p), "v"(v) : "memory");
}
__device__ __forceinline__ void st_coh_u16(void* p, unsigned v){
    asm volatile("global_store_short %0, %1, off sc0 sc1" :: "v"(p), "v"(v) : "memory");
}
__device__ __forceinline__ void waitv0(){ asm volatile("s_waitcnt vmcnt(0)" ::: "memory"); }

// ---------------- prep: fp32 -> fp16 conversions ----------------
__global__ void cvt_f32_f16_k(const float* __restrict__ src, _Float16* __restrict__ dst, int n8) {
    int i = blockIdx.x*blockDim.x + threadIdx.x;
    if (i >= n8) return;
    const float4* s = (const float4*)src;
    float4 a = s[2*(size_t)i], b = s[2*(size_t)i+1];
    f16x8 o;
    o[0]=(_Float16)a.x; o[1]=(_Float16)a.y; o[2]=(_Float16)a.z; o[3]=(_Float16)a.w;
    o[4]=(_Float16)b.x; o[5]=(_Float16)b.y; o[6]=(_Float16)b.z; o[7]=(_Float16)b.w;
    *(f16x8*)(dst + 8*(size_t)i) = o;
}

__global__ void pack_w12_k(const float* __restrict__ W1, const float* __restrict__ W2,
                           _Float16* __restrict__ dst) {
    int i = blockIdx.x*blockDim.x + threadIdx.x;
    int n8 = 2048*K1/8;
    if (i >= n8) return;
    size_t e = 8*(size_t)i;
    const float* src = (e < (size_t)H_*K1) ? (W1 + e) : (W2 + e - (size_t)H_*K1);
    float4 a = *(const float4*)src;
    float4 b = *(const float4*)(src+4);
    f16x8 o;
    o[0]=(_Float16)a.x; o[1]=(_Float16)a.y; o[2]=(_Float16)a.z; o[3]=(_Float16)a.w;
    o[4]=(_Float16)b.x; o[5]=(_Float16)b.y; o[6]=(_Float16)b.z; o[7]=(_Float16)b.w;
    *(f16x8*)(dst + e) = o;
}

// ---------------- belta = exp(-relu(td @ Wb^T + bb)) ----------------
__global__ void __launch_bounds__(256) belta_gemm_k(const _Float16* __restrict__ td,
                                                    const _Float16* __restrict__ Wbh,
                                                    const float* __restrict__ bb,
                                                    _Float16* __restrict__ belta) {
    __shared__ _Float16 As[64][136];
    __shared__ _Float16 Bs[128][136];
    const int bid = blockIdx.x;
    const int mt = bid >> 3, nt = bid & 7;
    const int bt0 = mt*64, h0 = nt*128;
    const int tid = threadIdx.x;
    const int w = tid >> 6, l = tid & 63;
    const int wm = (w>>1)*32, wn = (w&1)*64;
    f32x4 acc[2][4] = {};
    for (int kc = 0; kc < 4; ++kc) {
        const int kbase = kc*128;
        #pragma unroll
        for (int p = 0; p < 4; ++p) {
            int unit = tid + 256*p; int r = unit>>4, cu = unit&15;
            *(uint4*)&As[r][cu*8] = *(const uint4*)(td + (size_t)(bt0+r)*IN_ + kbase + cu*8);
        }
        #pragma unroll
        for (int p = 0; p < 8; ++p) {
            int unit = tid + 256*p; int r = unit>>4, cu = unit&15;
            *(uint4*)&Bs[r][cu*8] = *(const uint4*)(Wbh + (size_t)(h0+r)*IN_ + kbase + cu*8);
        }
        __syncthreads();
        #pragma unroll
        for (int ks = 0; ks < 4; ++ks) {
            const int kk = ks*32 + (l>>4)*8;
            f16x8 a0 = *(const f16x8*)&As[wm +      (l&15)][kk];
            f16x8 a1 = *(const f16x8*)&As[wm + 16 + (l&15)][kk];
            #pragma unroll
            for (int ni = 0; ni < 4; ++ni) {
                f16x8 b = *(const f16x8*)&Bs[wn + ni*16 + (l&15)][kk];
                acc[0][ni] = __builtin_amdgcn_mfma_f32_16x16x32_f16(a0, b, acc[0][ni], 0,0,0);
                acc[1][ni] = __builtin_amdgcn_mfma_f32_16x16x32_f16(a1, b, acc[1][ni], 0,0,0);
            }
        }
        __syncthreads();
    }
    #pragma unroll
    for (int mi = 0; mi < 2; ++mi)
    #pragma unroll
    for (int ni = 0; ni < 4; ++ni)
    #pragma unroll
    for (int r = 0; r < 4; ++r) {
        int m_l = wm + mi*16 + (l>>4)*4 + r;
        int n_l = wn + ni*16 + (l&15);
        int bt = bt0 + m_l, h = h0 + n_l;
        float z = acc[mi][ni][r] + bb[h];
        belta[(size_t)bt*H_ + h] = (_Float16)__expf(-fmaxf(z, 0.f));
    }
}

// ---------------- grid barrier: RELAXED agent atomics only ----------------
// No acquire/release -> no L2 writeback/invalidate. Data exchange goes through
// sc0 sc1 accesses which are coherent by construction.
__device__ __forceinline__ void grid_barrier(int* flags, int it) {
    __syncthreads();                       // all waves drained own vmcnt here
    if (threadIdx.x == 0)
        __hip_atomic_store(&flags[blockIdx.x], it, __ATOMIC_RELAXED, __HIP_MEMORY_SCOPE_AGENT);
    for (;;) {
        int v = __hip_atomic_load(&flags[threadIdx.x], __ATOMIC_RELAXED, __HIP_MEMORY_SCOPE_AGENT);
        if (__syncthreads_count(v < it) == 0) break;
        __builtin_amdgcn_s_sleep(4);
    }
}

// ---------------- recurrent scan ----------------
__global__ void __launch_bounds__(256) recur_k(
    const _Float16* __restrict__ xh,     // (B,T,IN)  plain cached
    const _Float16* __restrict__ belta,  // (B,T,H)   plain cached
    const _Float16* __restrict__ W12h,   // (2048,1536) plain cached (L2-hot)
    const _Float16* __restrict__ W3h,    // (1024,1536) plain cached (L2-hot)
    const float* __restrict__ b1, const float* __restrict__ b2, const float* __restrict__ b3,
    const float* __restrict__ Wo, const float* __restrict__ bo,
    float* __restrict__ S,               // (256,1024) fp32 scaled state — block-LOCAL tiles
    _Float16* __restrict__ ssh,          // fp16 scaled state — COHERENT exchange
    float* __restrict__ U,               // (256,1024) fp32 u-gate — COHERENT exchange
    _Float16* __restrict__ rsh,          // (256,1024) r*state — COHERENT exchange
    int* flags, float* __restrict__ out)
{
    __shared__ _Float16 As[32][264];
    __shared__ _Float16 Bs[64][264];
    __shared__ float red[4];
    const int bid = blockIdx.x, tid = threadIdx.x;
    const int w = tid>>6, l = tid&63;
    const int mg = bid>>5, ng = bid&31;
    const int m0 = mg*32;
    int it = 0;

    for (int t = 0; t < T_; ++t) {
        { // ---- P1: [u|r] = sigmoid([sstate|x_t] @ W12^T + b), tile 32x64, BK=256 ----
            const int n0 = ng*64;
            const int wm = (w>>1)*16, wn = (w&1)*32;
            f32x4 acc[2] = {};
            for (int kc = 0; kc < 6; ++kc) {
                const int kbase = kc*256;
                uint4 ta[4], tb[8];
                if (kc < 4) {
                    #pragma unroll
                    for (int p=0;p<4;++p){ int unit=tid+256*p; int r=unit>>5, cu=unit&31;
                        ta[p] = ld_coh_b128_nw(ssh + (size_t)(m0+r)*H_ + kbase + cu*8); }
                } else {
                    #pragma unroll
                    for (int p=0;p<4;++p){ int unit=tid+256*p; int r=unit>>5, cu=unit&31;
                        ta[p] = *(const uint4*)(xh + ((size_t)(m0+r)*T_ + t)*IN_ + (kbase-H_) + cu*8); }
                }
                #pragma unroll
                for (int p=0;p<8;++p){ int unit=tid+256*p; int r=unit>>5, cu=unit&31;
                    tb[p] = *(const uint4*)(W12h + (size_t)(n0+r)*K1 + kbase + cu*8); }
                waitv0();
                #pragma unroll
                for (int p=0;p<4;++p){ int unit=tid+256*p; int r=unit>>5, cu=unit&31;
                    *(uint4*)&As[r][cu*8] = ta[p]; }
                #pragma unroll
                for (int p=0;p<8;++p){ int unit=tid+256*p; int r=unit>>5, cu=unit&31;
                    *(uint4*)&Bs[r][cu*8] = tb[p]; }
                __syncthreads();
                #pragma unroll
                for (int ks = 0; ks < 8; ++ks) {
                    const int kk = ks*32 + (l>>4)*8;
                    f16x8 a = *(const f16x8*)&As[wm + (l&15)][kk];
                    #pragma unroll
                    for (int ni = 0; ni < 2; ++ni) {
                        f16x8 b = *(const f16x8*)&Bs[wn + ni*16 + (l&15)][kk];
                        acc[ni] = __builtin_amdgcn_mfma_f32_16x16x32_f16(a, b, acc[ni], 0,0,0);
                    }
                }
                __syncthreads();
            }
            if (n0 < H_) {      // u-columns
                #pragma unroll
                for (int ni=0;ni<2;++ni)
                #pragma unroll
                for (int r=0;r<4;++r) {
                    int m = m0 + wm + (l>>4)*4 + r;
                    int n = n0 + wn + ni*16 + (l&15);
                    float u = sigmoidf_(acc[ni][r] + b1[n]);
                    st_coh_u32(&U[(size_t)m*H_ + n], __float_as_uint(u));
                }
            } else {            // r-columns -> rsh = sigmoid(.)*sstate
                unsigned sv[8];
                #pragma unroll
                for (int ni=0;ni<2;++ni)
                #pragma unroll
                for (int r=0;r<4;++r) {
                    int m = m0 + wm + (l>>4)*4 + r;
                    int h = n0 - H_ + wn + ni*16 + (l&15);
                    sv[ni*4+r] = ld_coh_u16_nw(ssh + (size_t)m*H_ + h);
                }
                waitv0();
                #pragma unroll
                for (int ni=0;ni<2;++ni)
                #pragma unroll
                for (int r=0;r<4;++r) {
                    int m = m0 + wm + (l>>4)*4 + r;
                    int h = n0 - H_ + wn + ni*16 + (l&15);
                    unsigned short us = (unsigned short)sv[ni*4+r];
                    float sval = (float)(*(_Float16*)&us);
                    float rr = sigmoidf_(acc[ni][r] + b2[h]);
                    _Float16 hv = (_Float16)(rr * sval);
                    st_coh_u16(rsh + (size_t)m*H_ + h, (unsigned)*(unsigned short*)&hv);
                }
            }
        }
        grid_barrier(flags, ++it);
        { // ---- P2: nst = tanh([r*sstate|x_t] @ W3^T + b3); update; tile 32x32, BK=256 ----
            const int n0 = ng*32;
            const int wm = (w>>1)*16, wn = (w&1)*16;
            f32x4 acc = {};
            for (int kc = 0; kc < 6; ++kc) {
                const int kbase = kc*256;
                uint4 ta[4], tb[4];
                if (kc < 4) {
                    #pragma unroll
                    for (int p=0;p<4;++p){ int unit=tid+256*p; int r=unit>>5, cu=unit&31;
                        ta[p] = ld_coh_b128_nw(rsh + (size_t)(m0+r)*H_ + kbase + cu*8); }
                } else {
                    #pragma unroll
                    for (int p=0;p<4;++p){ int unit=tid+256*p; int r=unit>>5, cu=unit&31;
                        ta[p] = *(const uint4*)(xh + ((size_t)(m0+r)*T_ + t)*IN_ + (kbase-H_) + cu*8); }
                }
                #pragma unroll
                for (int p=0;p<4;++p){ int unit=tid+256*p; int r=unit>>5, cu=unit&31;
                    tb[p] = *(const uint4*)(W3h + (size_t)(n0+r)*K1 + kbase + cu*8); }
                waitv0();
                #pragma unroll
                for (int p=0;p<4;++p){ int unit=tid+256*p; int r=unit>>5, cu=unit&31;
                    *(uint4*)&As[r][cu*8] = ta[p]; }
                #pragma unroll
                for (int p=0;p<4;++p){ int unit=tid+256*p; int r=unit>>5, cu=unit&31;
                    *(uint4*)&Bs[r][cu*8] = tb[p]; }
                __syncthreads();
                #pragma unroll
                for (int ks = 0; ks < 8; ++ks) {
                    const int kk = ks*32 + (l>>4)*8;
                    f16x8 a = *(const f16x8*)&As[wm + (l&15)][kk];
                    f16x8 b = *(const f16x8*)&Bs[wn + (l&15)][kk];
                    acc = __builtin_amdgcn_mfma_f32_16x16x32_f16(a, b, acc, 0,0,0);
                }
                __syncthreads();
            }
            // epilogue: state update (S tile is block-local; U coherent; ssh coherent out)
            unsigned uv[4];
            const int n = n0 + wn + (l&15);
            #pragma unroll
            for (int r=0;r<4;++r) {
                int m = m0 + wm + (l>>4)*4 + r;
                uv[r] = ld_coh_u32_nw(&U[(size_t)m*H_ + n]);
            }
            waitv0();
            #pragma unroll
            for (int r=0;r<4;++r) {
                int m = m0 + wm + (l>>4)*4 + r;
                size_t idx = (size_t)m*H_ + n;
                float u = __uint_as_float(uv[r]);
                float nst = tanhf_(acc[r] + b3[n]);
                float snew = (1.f - u)*S[idx] + u*nst;
                if (t < T_-1) {
                    float bel = (float)belta[((size_t)m*T_ + (t+1))*H_ + n];
                    float ss = bel * snew;
                    S[idx] = ss;                       // plain (block-local reuse)
                    _Float16 hs = (_Float16)ss;
                    st_coh_u16(ssh + idx, (unsigned)*(unsigned short*)&hs);
                } else {
                    _Float16 hs = (_Float16)snew;      // final state, unscaled
                    st_coh_u16(ssh + idx, (unsigned)*(unsigned short*)&hs);
                }
            }
        }
        grid_barrier(flags, ++it);
    }
    // ---- final: out[b] = sigmoid(ssh[b,:] . Wo + bo) (ssh coherent) ----
    {
        uint2 sv = ld_coh_b64_nw(ssh + (size_t)bid*H_ + tid*4);
        waitv0();
        const _Float16* hp = (const _Float16*)&sv;
        float sum = 0.f;
        #pragma unroll
        for (int j=0;j<4;++j) sum += (float)hp[j] * Wo[tid*4 + j];
        #pragma unroll
        for (int off = 32; off; off >>= 1) sum += __shfl_down(sum, off, 64);
        if (l == 0) red[w] = sum;
        __syncthreads();
        if (tid == 0) out[bid] = sigmoidf_(red[0]+red[1]+red[2]+red[3] + bo[0]);
    }
}

extern "C" void kernel_launch(void* const* d_in, const int* in_sizes, int n_in,
                              void* d_out, int out_size, void* d_ws, size_t ws_size,
                              hipStream_t stream) {
    const float* x   = (const float*)d_in[0];
    const float* td  = (const float*)d_in[1];
    const float* Wb  = (const float*)d_in[2];
    const float* bb  = (const float*)d_in[3];
    const float* W1  = (const float*)d_in[4];
    const float* b1  = (const float*)d_in[5];
    const float* W2  = (const float*)d_in[6];
    const float* b2  = (const float*)d_in[7];
    const float* W3  = (const float*)d_in[8];
    const float* b3  = (const float*)d_in[9];
    const float* Wo  = (const float*)d_in[10];
    const float* bo  = (const float*)d_in[11];
    float* out = (float*)d_out;

    char* p = (char*)d_ws;
    auto carve = [&](size_t bytes) { char* r = p; p += (bytes + 255) & ~(size_t)255; return r; };
    int*      bar  = (int*)      carve(4096);
    float*    S    = (float*)    carve((size_t)B_*H_*4);
    _Float16* ssh  = (_Float16*) carve((size_t)B_*H_*2);
    float*    U    = (float*)    carve((size_t)B_*H_*4);
    _Float16* rsh  = (_Float16*) carve((size_t)B_*H_*2);
    _Float16* xh   = (_Float16*) carve((size_t)NT*IN_*2);
    _Float16* tdh  = (_Float16*) carve((size_t)NT*IN_*2);
    _Float16* belh = (_Float16*) carve((size_t)NT*H_*2);
    _Float16* W12h = (_Float16*) carve((size_t)2048*K1*2);
    _Float16* W3h  = (_Float16*) carve((size_t)H_*K1*2);
    _Float16* Wbh  = (_Float16*) carve((size_t)H_*IN_*2);

    // zero barrier flags + S + ssh (contiguous at the front of d_ws)
    size_t zbytes = 4096 + (size_t)B_*H_*4 + (size_t)B_*H_*2;
    hipMemsetAsync(bar, 0, zbytes, stream);

    const int thr = 256;
    int n8;
    n8 = NT*IN_/8;    cvt_f32_f16_k<<<(n8+thr-1)/thr, thr, 0, stream>>>(x,  xh,  n8);
    n8 = NT*IN_/8;    cvt_f32_f16_k<<<(n8+thr-1)/thr, thr, 0, stream>>>(td, tdh, n8);
    n8 = H_*K1/8;     cvt_f32_f16_k<<<(n8+thr-1)/thr, thr, 0, stream>>>(W3, W3h, n8);
    n8 = H_*IN_/8;    cvt_f32_f16_k<<<(n8+thr-1)/thr, thr, 0, stream>>>(Wb, Wbh, n8);
    n8 = 2048*K1/8;   pack_w12_k<<<(n8+thr-1)/thr, thr, 0, stream>>>(W1, W2, W12h);

    belta_gemm_k<<<(NT/64)*(H_/128), 256, 0, stream>>>(tdh, Wbh, bb, belh);

    recur_k<<<256, 256, 0, stream>>>(xh, belh, W12h, W3h, b1, b2, b3, Wo, bo,
                                     S, ssh, U, rsh, bar, out);
}

// Round 5
// 2220.121 us; speedup vs baseline: 4.0155x; 1.9193x over previous
//
#include <hip/hip_runtime.h>
#include <hip/hip_fp16.h>

#define B_  256
#define T_  96
#define IN_ 512
#define H_  1024
#define K1  1536          // H + IN
#define NT  (B_*T_)       // 24576

// recur_k: 4 groups x 64 blocks; group owns 64 batch rows; block owns 16 cols
// of W1/W2/W3 (rows 16j..16j+16 of each). Persistent LDS weights only:
#define W12_OFF 0          // 32 rows x 3072 B  (W1 slice rows 0-15, W2 rows 16-31)
#define W3_OFF  98304      // 16 rows x 3072 B
#define WROW    3072       // 147456 B total (<= ~163584 usable)

typedef _Float16 f16x8 __attribute__((ext_vector_type(8)));
typedef float    f32x4 __attribute__((ext_vector_type(4)));

__device__ __forceinline__ float sigmoidf_(float z) { return 1.f/(1.f+__expf(-z)); }
__device__ __forceinline__ float tanhf_(float z)    { return 1.f - 2.f/(__expf(2.f*z)+1.f); }

// coherent (cross-XCD) access: bypass L1 + per-XCD L2, straight to coherence pt
__device__ __forceinline__ uint4 ld_coh_b128(const void* p){
    uint4 r; asm volatile("global_load_dwordx4 %0, %1, off sc0 sc1" : "=&v"(r) : "v"(p)); return r;
}
__device__ __forceinline__ uint4 ld_b128(const void* p){
    uint4 r; asm volatile("global_load_dwordx4 %0, %1, off" : "=&v"(r) : "v"(p)); return r;
}
__device__ __forceinline__ void st_coh_u16(void* p, unsigned v){
    asm volatile("global_store_short %0, %1, off sc0 sc1" :: "v"(p), "v"(v) : "memory");
}
#define WAITV(n) do { asm volatile("s_waitcnt vmcnt(" #n ")" ::: "memory"); \
                      __builtin_amdgcn_sched_barrier(0); } while(0)
__device__ __forceinline__ void waitv0_(){ asm volatile("s_waitcnt vmcnt(0)" ::: "memory"); }

// ---------------- prep: fp32 -> fp16 ----------------
__global__ void cvt_f32_f16_k(const float* __restrict__ src, _Float16* __restrict__ dst, int n8) {
    int i = blockIdx.x*blockDim.x + threadIdx.x;
    if (i >= n8) return;
    const float4* s = (const float4*)src;
    float4 a = s[2*(size_t)i], b = s[2*(size_t)i+1];
    f16x8 o;
    o[0]=(_Float16)a.x; o[1]=(_Float16)a.y; o[2]=(_Float16)a.z; o[3]=(_Float16)a.w;
    o[4]=(_Float16)b.x; o[5]=(_Float16)b.y; o[6]=(_Float16)b.z; o[7]=(_Float16)b.w;
    *(f16x8*)(dst + 8*(size_t)i) = o;
}

// ---------------- belta = exp(-relu(td @ Wb^T + bb)) ----------------
__global__ void __launch_bounds__(256) belta_gemm_k(const _Float16* __restrict__ td,
                                                    const _Float16* __restrict__ Wbh,
                                                    const float* __restrict__ bb,
                                                    _Float16* __restrict__ belta) {
    __shared__ _Float16 As[64][136];
    __shared__ _Float16 Bs[128][136];
    const int bid = blockIdx.x;
    const int mt = bid >> 3, nt = bid & 7;
    const int bt0 = mt*64, h0 = nt*128;
    const int tid = threadIdx.x;
    const int w = tid >> 6, l = tid & 63;
    const int wm = (w>>1)*32, wn = (w&1)*64;
    f32x4 acc[2][4] = {};
    for (int kc = 0; kc < 4; ++kc) {
        const int kbase = kc*128;
        #pragma unroll
        for (int p = 0; p < 4; ++p) {
            int unit = tid + 256*p; int r = unit>>4, cu = unit&15;
            *(uint4*)&As[r][cu*8] = *(const uint4*)(td + (size_t)(bt0+r)*IN_ + kbase + cu*8);
        }
        #pragma unroll
        for (int p = 0; p < 8; ++p) {
            int unit = tid + 256*p; int r = unit>>4, cu = unit&15;
            *(uint4*)&Bs[r][cu*8] = *(const uint4*)(Wbh + (size_t)(h0+r)*IN_ + kbase + cu*8);
        }
        __syncthreads();
        #pragma unroll
        for (int ks = 0; ks < 4; ++ks) {
            const int kk = ks*32 + (l>>4)*8;
            f16x8 a0 = *(const f16x8*)&As[wm +      (l&15)][kk];
            f16x8 a1 = *(const f16x8*)&As[wm + 16 + (l&15)][kk];
            #pragma unroll
            for (int ni = 0; ni < 4; ++ni) {
                f16x8 b = *(const f16x8*)&Bs[wn + ni*16 + (l&15)][kk];
                acc[0][ni] = __builtin_amdgcn_mfma_f32_16x16x32_f16(a0, b, acc[0][ni], 0,0,0);
                acc[1][ni] = __builtin_amdgcn_mfma_f32_16x16x32_f16(a1, b, acc[1][ni], 0,0,0);
            }
        }
        __syncthreads();
    }
    #pragma unroll
    for (int mi = 0; mi < 2; ++mi)
    #pragma unroll
    for (int ni = 0; ni < 4; ++ni)
    #pragma unroll
    for (int r = 0; r < 4; ++r) {
        int m_l = wm + mi*16 + (l>>4)*4 + r;
        int n_l = wn + ni*16 + (l&15);
        int bt = bt0 + m_l, h = h0 + n_l;
        float z = acc[mi][ni][r] + bb[h];
        belta[(size_t)bt*H_ + h] = (_Float16)__expf(-fmaxf(z, 0.f));
    }
}

// ---------------- group barrier (64 blocks, relaxed agent atomics) ----------------
__device__ __forceinline__ void group_barrier(int* flags, int gbase, int j, int it) {
    waitv0_();                 // drain inline-asm stores before publishing
    __syncthreads();
    if (threadIdx.x == 0)
        __hip_atomic_store(&flags[gbase + j], it, __ATOMIC_RELAXED, __HIP_MEMORY_SCOPE_AGENT);
    for (;;) {
        int v = __hip_atomic_load(&flags[gbase + (threadIdx.x & 63)],
                                  __ATOMIC_RELAXED, __HIP_MEMORY_SCOPE_AGENT);
        if (__syncthreads_count(v < it) == 0) break;
        __builtin_amdgcn_s_sleep(4);
    }
}

// ---------------- recurrent scan: LDS weights + fragment-direct A ----------------
__global__ void __launch_bounds__(256, 1) recur_k(
    const _Float16* __restrict__ xh,     // (B,T,IN) fp16, plain cached
    const _Float16* __restrict__ belh,   // (B,T,H) fp16, plain cached
    const float* __restrict__ W1, const float* __restrict__ W2, const float* __restrict__ W3,
    const float* __restrict__ b1, const float* __restrict__ b2, const float* __restrict__ b3,
    const float* __restrict__ Wo,
    _Float16* __restrict__ ssh,          // (256,1024) scaled state — coherent exchange
    _Float16* __restrict__ rsh,          // (256,1024) r*state — coherent exchange
    int* flags, float* __restrict__ outacc)
{
    __shared__ __align__(16) char smem[147456];
    const int bid = blockIdx.x, tid = threadIdx.x;
    const int g = bid >> 6, j = bid & 63;
    const int gbase = g*64, grow0 = g*64;
    const int w = tid >> 6;              // wave = M-fragment index (rows w*16..w*16+15)
    const int l = tid & 63;
    const int lh = l >> 4;               // k-slot
    const int ll = l & 15;               // col / A-row / B-row within fragment

    // ---- prologue: persistent weight slices -> LDS (f32->f16, XOR-swizzled) ----
    for (int u = tid; u < 32*192; u += 256) {        // W12: 32 rows x 192 16B-slots
        int row = u / 192, slot = u - row*192;
        const float* src = (row < 16) ? (W1 + ((size_t)(16*j + row))*K1 + slot*8)
                                      : (W2 + ((size_t)(16*j + row-16))*K1 + slot*8);
        float4 f0 = *(const float4*)src, f1 = *(const float4*)(src+4);
        f16x8 h;
        h[0]=(_Float16)f0.x; h[1]=(_Float16)f0.y; h[2]=(_Float16)f0.z; h[3]=(_Float16)f0.w;
        h[4]=(_Float16)f1.x; h[5]=(_Float16)f1.y; h[6]=(_Float16)f1.z; h[7]=(_Float16)f1.w;
        *(f16x8*)(smem + W12_OFF + row*WROW + ((slot*16) ^ ((row&7)<<4))) = h;
    }
    for (int u = tid; u < 16*192; u += 256) {        // W3: 16 rows x 192 slots
        int row = u / 192, slot = u - row*192;
        const float* src = W3 + ((size_t)(16*j + row))*K1 + slot*8;
        float4 f0 = *(const float4*)src, f1 = *(const float4*)(src+4);
        f16x8 h;
        h[0]=(_Float16)f0.x; h[1]=(_Float16)f0.y; h[2]=(_Float16)f0.z; h[3]=(_Float16)f0.w;
        h[4]=(_Float16)f1.x; h[5]=(_Float16)f1.y; h[6]=(_Float16)f1.z; h[7]=(_Float16)f1.w;
        *(f16x8*)(smem + W3_OFF + row*WROW + ((slot*16) ^ ((row&7)<<4))) = h;
    }
    __syncthreads();

    const int colU = (j<<4) + ll;                    // owned output column
    const float b1c = b1[colU], b2c = b2[colU], b3c = b3[colU];
    const float woc = Wo[colU];

    // per-lane A-load bases: row = grow0 + w*16 + ll, k-offset lh*8
    const _Float16* srow_s = ssh + ((size_t)(grow0 + w*16 + ll) << 10) + lh*8;
    const _Float16* srow_r = rsh + ((size_t)(grow0 + w*16 + ll) << 10) + lh*8;
    const _Float16* xrow   = xh + (size_t)(grow0 + w*16 + ll) * T_ * IN_ + lh*8;
    // per-lane C/epilogue rows: grow0 + w*16 + lh*4 + r, col colU
    const int crow0 = grow0 + w*16 + lh*4;

    float S_reg[4] = {0.f,0.f,0.f,0.f};
    float pout[4]  = {0.f,0.f,0.f,0.f};
    int it = 0;

    for (int t = 0; t < T_; ++t) {
        const _Float16* xrt = xrow + (size_t)t * IN_;
        float u_reg[4];
        { // ---- P1: [u|r] = sigmoid([state|x_t] @ W12^T + b) ----
            f32x4 acc1[2] = {};
            uint4 ab[5][4];
            #define ISSUE1(S, DST) do { \
                if ((S) < 8) { _Pragma("unroll") for (int kf=0;kf<4;++kf) \
                    DST[kf] = ld_coh_b128(srow_s + (S)*128 + kf*32); } \
                else { _Pragma("unroll") for (int kf=0;kf<4;++kf) \
                    DST[kf] = ld_b128(xrt + ((S)-8)*128 + kf*32); } } while(0)
            ISSUE1(0, ab[0]); ISSUE1(1, ab[1]); ISSUE1(2, ab[2]); ISSUE1(3, ab[3]);
            #pragma unroll
            for (int s = 0; s < 12; ++s) {
                if (s+4 < 12) ISSUE1(s+4, ab[(s+4)%5]);
                if      (s <= 7) { WAITV(16); }
                else if (s == 8) { WAITV(12); }
                else if (s == 9) { WAITV(8);  }
                else if (s ==10) { WAITV(4);  }
                else             { WAITV(0);  }
                #pragma unroll
                for (int kf = 0; kf < 4; ++kf) {
                    f16x8 a = *(const f16x8*)&ab[s%5][kf];
                    #pragma unroll
                    for (int nf = 0; nf < 2; ++nf) {
                        const int br = nf*16 + ll;
                        f16x8 b = *(const f16x8*)(smem + W12_OFF + br*WROW
                                    + ((s*256 + kf*64 + lh*16) ^ ((ll&7)<<4)));
                        acc1[nf] = __builtin_amdgcn_mfma_f32_16x16x32_f16(a, b, acc1[nf], 0,0,0);
                    }
                }
            }
            #undef ISSUE1
            #pragma unroll
            for (int r = 0; r < 4; ++r) {
                u_reg[r] = sigmoidf_(acc1[0][r] + b1c);
                float rr = sigmoidf_(acc1[1][r] + b2c);
                _Float16 hv = (_Float16)(rr * S_reg[r]);
                st_coh_u16(rsh + ((size_t)(crow0 + r) << 10) + colU,
                           (unsigned)*(unsigned short*)&hv);
            }
        }
        group_barrier(flags, gbase, j, ++it);
        { // ---- P2: ns = tanh([r*s|x_t] @ W3^T + b3); state update ----
            f32x4 acc2 = {};
            uint4 ab[5][4];
            #define ISSUE2(S, DST) do { \
                if ((S) < 8) { _Pragma("unroll") for (int kf=0;kf<4;++kf) \
                    DST[kf] = ld_coh_b128(srow_r + (S)*128 + kf*32); } \
                else { _Pragma("unroll") for (int kf=0;kf<4;++kf) \
                    DST[kf] = ld_b128(xrt + ((S)-8)*128 + kf*32); } } while(0)
            ISSUE2(0, ab[0]); ISSUE2(1, ab[1]); ISSUE2(2, ab[2]); ISSUE2(3, ab[3]);
            #pragma unroll
            for (int s = 0; s < 12; ++s) {
                if (s+4 < 12) ISSUE2(s+4, ab[(s+4)%5]);
                if      (s <= 7) { WAITV(16); }
                else if (s == 8) { WAITV(12); }
                else if (s == 9) { WAITV(8);  }
                else if (s ==10) { WAITV(4);  }
                else             { WAITV(0);  }
                #pragma unroll
                for (int kf = 0; kf < 4; ++kf) {
                    f16x8 a = *(const f16x8*)&ab[s%5][kf];
                    f16x8 b = *(const f16x8*)(smem + W3_OFF + ll*WROW
                                + ((s*256 + kf*64 + lh*16) ^ ((ll&7)<<4)));
                    acc2 = __builtin_amdgcn_mfma_f32_16x16x32_f16(a, b, acc2, 0,0,0);
                }
            }
            #undef ISSUE2
            #pragma unroll
            for (int r = 0; r < 4; ++r) {
                float ns = tanhf_(acc2[r] + b3c);
                float sn = (1.f - u_reg[r])*S_reg[r] + u_reg[r]*ns;
                if (t < T_-1) {
                    float bel = (float)belh[((size_t)(crow0 + r)*T_ + (t+1))*H_ + colU];
                    float ss = bel * sn;
                    S_reg[r] = ss;
                    _Float16 hs = (_Float16)ss;
                    st_coh_u16(ssh + ((size_t)(crow0 + r) << 10) + colU,
                               (unsigned)*(unsigned short*)&hs);
                } else {
                    pout[r] = sn * woc;
                }
            }
        }
        group_barrier(flags, gbase, j, ++it);
    }
    // ---- final: sum pout over the block's 16 cols (ll), atomicAdd per row ----
    #pragma unroll
    for (int r = 0; r < 4; ++r) {
        float v = pout[r];
        v += __shfl_xor(v, 1, 64);
        v += __shfl_xor(v, 2, 64);
        v += __shfl_xor(v, 4, 64);
        v += __shfl_xor(v, 8, 64);
        if (ll == 0) atomicAdd(&outacc[crow0 + r], v);
    }
}

__global__ void finish_k(const float* __restrict__ acc, const float* __restrict__ bo,
                         float* __restrict__ out) {
    int i = threadIdx.x;
    out[i] = sigmoidf_(acc[i] + bo[0]);
}

extern "C" void kernel_launch(void* const* d_in, const int* in_sizes, int n_in,
                              void* d_out, int out_size, void* d_ws, size_t ws_size,
                              hipStream_t stream) {
    const float* x   = (const float*)d_in[0];
    const float* td  = (const float*)d_in[1];
    const float* Wb  = (const float*)d_in[2];
    const float* bb  = (const float*)d_in[3];
    const float* W1  = (const float*)d_in[4];
    const float* b1  = (const float*)d_in[5];
    const float* W2  = (const float*)d_in[6];
    const float* b2  = (const float*)d_in[7];
    const float* W3  = (const float*)d_in[8];
    const float* b3  = (const float*)d_in[9];
    const float* Wo  = (const float*)d_in[10];
    const float* bo  = (const float*)d_in[11];
    float* out = (float*)d_out;

    char* p = (char*)d_ws;
    auto carve = [&](size_t bytes) { char* r = p; p += (bytes + 255) & ~(size_t)255; return r; };
    int*      bar    = (int*)      carve(1024);            // 256 flags
    float*    outacc = (float*)    carve(1024);            // 256 partial sums
    _Float16* ssh    = (_Float16*) carve((size_t)B_*H_*2); // scaled state exchange
    _Float16* rsh    = (_Float16*) carve((size_t)B_*H_*2); // r*state exchange
    _Float16* xh     = (_Float16*) carve((size_t)NT*IN_*2);
    _Float16* tdh    = (_Float16*) carve((size_t)NT*IN_*2);
    _Float16* belh   = (_Float16*) carve((size_t)NT*H_*2);
    _Float16* Wbh    = (_Float16*) carve((size_t)H_*IN_*2);

    // zero: flags + outacc + ssh (contiguous at front of d_ws)
    size_t zbytes = 1024 + 1024 + (size_t)B_*H_*2;
    (void)hipMemsetAsync(bar, 0, zbytes, stream);

    const int thr = 256;
    int n8;
    n8 = NT*IN_/8;    cvt_f32_f16_k<<<(n8+thr-1)/thr, thr, 0, stream>>>(x,  xh,  n8);
    n8 = NT*IN_/8;    cvt_f32_f16_k<<<(n8+thr-1)/thr, thr, 0, stream>>>(td, tdh, n8);
    n8 = H_*IN_/8;    cvt_f32_f16_k<<<(n8+thr-1)/thr, thr, 0, stream>>>(Wb, Wbh, n8);

    belta_gemm_k<<<(NT/64)*(H_/128), 256, 0, stream>>>(tdh, Wbh, bb, belh);

    recur_k<<<256, 256, 0, stream>>>(xh, belh, W1, W2, W3, b1, b2, b3, Wo,
                                     ssh, rsh, bar, outacc);
    finish_k<<<1, 256, 0, stream>>>(outacc, bo, out);
}